// Round 11
// baseline (224.556 us; speedup 1.0000x reference)
//
#include <hip/hip_runtime.h>

#define NUM_E 1024
#define DIM 64
#define NROWS 65536                  // 64*32*32
#define OUT0_SIZE 4194304            // 64*64*32*32
#define OUT1_OFF OUT0_SIZE
#define LOSS_OFF (OUT0_SIZE + 65536) // 4259840
#define KSPLIT 4
#define KCHUNK (NUM_E / KSPLIT)      // 256 codes per wave-slice

// ---------------- prep: En_k = np.sum(e_k*e_k) in numpy pairwise order ----
__device__ __forceinline__ float np_sumsq64_arr(const float* __restrict__ x) {
#pragma clang fp contract(off)
    float r[8];
#pragma unroll
    for (int j = 0; j < 8; ++j) r[j] = x[j] * x[j];
#pragma unroll
    for (int i = 8; i < 64; i += 8) {
#pragma unroll
        for (int j = 0; j < 8; ++j) {
            float p = x[i + j] * x[i + j];
            r[j] = r[j] + p;
        }
    }
    return ((r[0] + r[1]) + (r[2] + r[3])) + ((r[4] + r[5]) + (r[6] + r[7]));
}

__global__ __launch_bounds__(256) void vq_prep_kernel(const float* __restrict__ e,
                                                      float* __restrict__ En,
                                                      float* __restrict__ out) {
    const int k = blockIdx.x * 256 + threadIdx.x;   // grid covers 1024 exactly
    if (k == 0) out[LOSS_OFF] = 0.0f;               // d_out re-poisoned every call
    float xr[DIM];
    const float4* ep = (const float4*)(e + (size_t)k * DIM);
#pragma unroll
    for (int i = 0; i < 16; ++i) {
        float4 v = ep[i];
        xr[4*i+0] = v.x; xr[4*i+1] = v.y; xr[4*i+2] = v.z; xr[4*i+3] = v.w;
    }
    En[k] = np_sumsq64_arr(xr);
}

// ---------------- fused scan+finish ----------------
// z row = 64 named SCALAR floats, re-pinned with empty "+v" asm INSIDE the
// k-loop: the asm may "modify" them each iteration, so they are not
// rematerializable from memory and must stay live in VGPRs across the loop
// (R4-R9 failure: allocator sank z loads into the loop; outside-loop pins
// (R5) don't survive). e stays wave-uniform -> scalar cache. Sequential
// 64-FMA chain per code = bit-exact np/sgemm order (validated R3).
#define ZDEF(i)  float z##i##a, z##i##b, z##i##c, z##i##d
#define ZLOAD(i) { float4 v = zp[i]; z##i##a = v.x; z##i##b = v.y; z##i##c = v.z; z##i##d = v.w; }
#define ZPIN2(i, j)                                                            \
    do { asm volatile("" : "+v"(z##i##a), "+v"(z##i##b), "+v"(z##i##c),        \
                           "+v"(z##i##d), "+v"(z##j##a), "+v"(z##j##b),        \
                           "+v"(z##j##c), "+v"(z##j##d)); } while (0)

#define SQ8S(i, j)                                                     \
    { float p;                                                         \
      p = z##i##a*z##i##a; r0 = r0 + p;  p = z##i##b*z##i##b; r1 = r1 + p; \
      p = z##i##c*z##i##c; r2 = r2 + p;  p = z##i##d*z##i##d; r3 = r3 + p; \
      p = z##j##a*z##j##a; r4 = r4 + p;  p = z##j##b*z##j##b; r5 = r5 + p; \
      p = z##j##c*z##j##c; r6 = r6 + p;  p = z##j##d*z##j##d; r7 = r7 + p; }

#define DOT4S(Q)                                                       \
    { float4 ev = ep[Q];                                               \
      m = fmaf(ev.x, z##Q##a, m); m = fmaf(ev.y, z##Q##b, m);          \
      m = fmaf(ev.z, z##Q##c, m); m = fmaf(ev.w, z##Q##d, m); }

#define EPI4S(Q)                                                       \
    { float4 evv = erp[Q]; float df;                                   \
      o0[(size_t)(4*Q+0)*1024] = evv.x; df = evv.x - z##Q##a; lsum = fmaf(df,df,lsum); \
      o0[(size_t)(4*Q+1)*1024] = evv.y; df = evv.y - z##Q##b; lsum = fmaf(df,df,lsum); \
      o0[(size_t)(4*Q+2)*1024] = evv.z; df = evv.z - z##Q##c; lsum = fmaf(df,df,lsum); \
      o0[(size_t)(4*Q+3)*1024] = evv.w; df = evv.w - z##Q##d; lsum = fmaf(df,df,lsum); }

__global__
__attribute__((amdgpu_flat_work_group_size(256, 256), amdgpu_waves_per_eu(4, 4)))
void vq_fused_kernel(const float* __restrict__ z,
                     const float* __restrict__ e,
                     const float* __restrict__ En,
                     float* __restrict__ out) {
    const int lane = threadIdx.x & 63;
    const int q = __builtin_amdgcn_readfirstlane((int)(threadIdx.x >> 6)); // wave-uniform slice id
    const int n = blockIdx.x * 64 + lane;            // row

    ZDEF(0);  ZDEF(1);  ZDEF(2);  ZDEF(3);  ZDEF(4);  ZDEF(5);  ZDEF(6);  ZDEF(7);
    ZDEF(8);  ZDEF(9);  ZDEF(10); ZDEF(11); ZDEF(12); ZDEF(13); ZDEF(14); ZDEF(15);
    {
        const float4* zp = (const float4*)(z + (size_t)n * DIM);
        ZLOAD(0)  ZLOAD(1)  ZLOAD(2)  ZLOAD(3)  ZLOAD(4)  ZLOAD(5)  ZLOAD(6)  ZLOAD(7)
        ZLOAD(8)  ZLOAD(9)  ZLOAD(10) ZLOAD(11) ZLOAD(12) ZLOAD(13) ZLOAD(14) ZLOAD(15)
    }

    // A = np pairwise sum of z*z (bit-exact vs numpy, validated R3)
    float A;
    {
#pragma clang fp contract(off)
        float r0,r1,r2,r3,r4,r5,r6,r7;
        { float p;
          p = z0a*z0a; r0 = p;  p = z0b*z0b; r1 = p;
          p = z0c*z0c; r2 = p;  p = z0d*z0d; r3 = p;
          p = z1a*z1a; r4 = p;  p = z1b*z1b; r5 = p;
          p = z1c*z1c; r6 = p;  p = z1d*z1d; r7 = p; }
        SQ8S(2,  3)  SQ8S(4,  5)  SQ8S(6,  7)
        SQ8S(8,  9)  SQ8S(10, 11) SQ8S(12, 13) SQ8S(14, 15)
        A = ((r0 + r1) + (r2 + r3)) + ((r4 + r5) + (r6 + r7));
    }

    const int k0 = q * KCHUNK;
    float best = 3.4e38f;
    int bk = k0;
#pragma unroll 1
    for (int kk = 0; kk < KCHUNK; ++kk) {
        // Re-pin z every iteration: values become asm-modified -> must stay
        // live in VGPRs; loads cannot be sunk into the loop. Zero instructions.
        ZPIN2(0, 1);   ZPIN2(2, 3);   ZPIN2(4, 5);   ZPIN2(6, 7);
        ZPIN2(8, 9);   ZPIN2(10, 11); ZPIN2(12, 13); ZPIN2(14, 15);

        const int k = k0 + kk;
        const float4* ep = (const float4*)(e + (size_t)k * DIM);  // uniform -> s_load
        float m = 0.0f;                                  // sequential sgemm chain
        DOT4S(0)  DOT4S(1)  DOT4S(2)  DOT4S(3)
        DOT4S(4)  DOT4S(5)  DOT4S(6)  DOT4S(7)
        DOT4S(8)  DOT4S(9)  DOT4S(10) DOT4S(11)
        DOT4S(12) DOT4S(13) DOT4S(14) DOT4S(15)
        float s;
        {
#pragma clang fp contract(off)
            float twoM = 2.0f * m;                       // exact
            float t = A - twoM;                          // the ref's rounding grid
            s = t + En[k];
        }
        if (s < best) { best = s; bk = k; }              // strict < => first index
    }

    __shared__ float ls[KSPLIT][64];
    __shared__ int   li[KSPLIT][64];
    ls[q][lane] = best;
    li[q][lane] = bk;
    __syncthreads();

    if (threadIdx.x < 64) {                              // wave 0 does the epilogue
        float b0 = ls[0][lane];
        int   kb = li[0][lane];
#pragma unroll
        for (int qq = 1; qq < KSPLIT; ++qq) {
            float sq = ls[qq][lane];
            if (sq < b0) { b0 = sq; kb = li[qq][lane]; } // ascending q = ascending k
        }

        const int b  = n >> 10;      // H*W = 1024
        const int hw = n & 1023;
        const float4* erp = (const float4*)(e + (size_t)kb * DIM);  // L2-hot gather
        float* o0 = out + (size_t)b * 65536 + hw;        // out0[b, d, hw]
        float lsum = 0.0f;
        EPI4S(0)  EPI4S(1)  EPI4S(2)  EPI4S(3)
        EPI4S(4)  EPI4S(5)  EPI4S(6)  EPI4S(7)
        EPI4S(8)  EPI4S(9)  EPI4S(10) EPI4S(11)
        EPI4S(12) EPI4S(13) EPI4S(14) EPI4S(15)
        out[OUT1_OFF + n] = (float)kb;

#pragma unroll
        for (int off = 32; off > 0; off >>= 1)
            lsum += __shfl_down(lsum, off, 64);
        if (lane == 0)
            atomicAdd(&out[LOSS_OFF], lsum * (1.25f / 4194304.0f));
    }
}

extern "C" void kernel_launch(void* const* d_in, const int* in_sizes, int n_in,
                              void* d_out, int out_size, void* d_ws, size_t ws_size,
                              hipStream_t stream) {
    const float* z = (const float*)d_in[0];       // [65536, 64] fp32
    const float* e = (const float*)d_in[1];       // [1024, 64] fp32
    float* out = (float*)d_out;
    float* En  = (float*)d_ws;                    // 1024 fp32 norms (4 KB)

    vq_prep_kernel<<<NUM_E / 256, 256, 0, stream>>>(e, En, out);
    vq_fused_kernel<<<NROWS / 64, 256, 0, stream>>>(z, e, En, out);
}